// Round 1
// baseline (15.236 us; speedup 1.0000x reference)
//
#include <hip/hip_runtime.h>

// Problem constants (from reference)
#define B_ 64
#define L_ 2048
#define D_ 768
#define S_ 32
#define MSL_ 16

// One block per span. 192 threads; each thread owns one float4 (4 floats) of
// the D=768 channel dim (192 * 4 = 768). Loop over valid rows, accumulate,
// scale, store. Thread 0 also writes the span-valid mask element.
__global__ __launch_bounds__(192) void span_mean_kernel(
    const float* __restrict__ emb,      // (B, L, D)
    const int*   __restrict__ span_pos, // (B, S, 2)
    const int*   __restrict__ span_nums,// (B,)
    float*       __restrict__ out)      // pooled (B,S,D) then mask (B,S)
{
    const int sp = blockIdx.x;          // 0 .. B*S-1
    const int b  = sp >> 5;             // / S_ (S_ == 32)
    const int s  = sp & (S_ - 1);       // % S_

    // Reference adds +1 to stored positions.
    const int start = span_pos[sp * 2 + 0] + 1;
    const int end   = span_pos[sp * 2 + 1] + 1;

    int n = end - start;
    n = n < 0 ? 0 : (n > MSL_ ? MSL_ : n);       // valid count = clamp(end-start, 0, 16)
    const int   cnt = n > 0 ? n : 1;             // max(count, 1)
    const float inv = 1.0f / (float)cnt;
    const bool  span_valid = (s < span_nums[b]);

    const int t = threadIdx.x;                   // 0..191, float4 lane within row

    float4 acc = make_float4(0.f, 0.f, 0.f, 0.f);
    const float* embB = emb + (size_t)b * L_ * D_;
    for (int o = 0; o < n; ++o) {
        int pos = start + o;
        pos = pos < 0 ? 0 : (pos > (L_ - 1) ? (L_ - 1) : pos);  // ref clips
        const float4 v = *reinterpret_cast<const float4*>(embB + (size_t)pos * D_ + t * 4);
        acc.x += v.x; acc.y += v.y; acc.z += v.z; acc.w += v.w;
    }

    const float scale = span_valid ? inv : 0.0f;
    float4 r;
    r.x = acc.x * scale;
    r.y = acc.y * scale;
    r.z = acc.z * scale;
    r.w = acc.w * scale;

    *reinterpret_cast<float4*>(out + (size_t)sp * D_ + t * 4) = r;

    if (t == 0) {
        // mask output lives after pooled: offset B*S*D + sp, written as 1.0/0.0
        out[(size_t)B_ * S_ * D_ + sp] = span_valid ? 1.0f : 0.0f;
    }
}

extern "C" void kernel_launch(void* const* d_in, const int* in_sizes, int n_in,
                              void* d_out, int out_size, void* d_ws, size_t ws_size,
                              hipStream_t stream) {
    const float* emb       = (const float*)d_in[0];
    const int*   span_pos  = (const int*)d_in[1];
    const int*   span_nums = (const int*)d_in[2];
    // d_in[3] (repeated_vector) is derivable / unused.
    float* out = (float*)d_out;

    span_mean_kernel<<<B_ * S_, 192, 0, stream>>>(emb, span_pos, span_nums, out);
}

// Round 2
// 14.672 us; speedup vs baseline: 1.0384x; 1.0384x over previous
//
#include <hip/hip_runtime.h>

// Problem constants (from reference)
#define B_ 64
#define L_ 2048
#define D_ 768
#define S_ 32
#define MSL_ 16

// One block per span. 192 threads; each thread owns one float4 (4 floats) of
// the D=768 channel dim (192 * 4 = 768). Fully-unrolled 16-row gather with
// unconditional loads (invalid offsets clamped to the last valid row -> L1
// hit, weighted by 0) so each wave keeps 16 loads in flight (MLP), instead of
// a runtime-trip-count loop that serializes one load per ~900-cycle HBM miss.
__global__ __launch_bounds__(192) void span_mean_kernel(
    const float* __restrict__ emb,      // (B, L, D)
    const int*   __restrict__ span_pos, // (B, S, 2)
    const int*   __restrict__ span_nums,// (B,)
    float*       __restrict__ out)      // pooled (B,S,D) then mask (B,S)
{
    const int sp = blockIdx.x;          // 0 .. B*S-1
    const int b  = sp >> 5;             // / S_ (S_ == 32)
    const int s  = sp & (S_ - 1);       // % S_

    // Reference adds +1 to stored positions.
    const int start = span_pos[sp * 2 + 0] + 1;
    const int end   = span_pos[sp * 2 + 1] + 1;

    int n = end - start;
    n = n < 0 ? 0 : (n > MSL_ ? MSL_ : n);       // valid count = clamp(end-start, 0, 16)
    const int   cnt = n > 0 ? n : 1;             // max(count, 1)
    const float inv = 1.0f / (float)cnt;
    const bool  span_valid = (s < span_nums[b]);

    const int t = threadIdx.x;                   // 0..191, float4 lane within row

    const float* embB = emb + (size_t)b * L_ * D_;

    // Issue all 16 loads unconditionally; out-of-span offsets re-read the
    // last valid row (L1 hit) with weight 0.
    float4 v[MSL_];
    float  w[MSL_];
#pragma unroll
    for (int o = 0; o < MSL_; ++o) {
        int oo = (o < n) ? o : (n - 1);          // clamp (n>=1 in practice)
        oo = oo < 0 ? 0 : oo;                    // guard n==0
        int pos = start + oo;
        pos = pos < 0 ? 0 : (pos > (L_ - 1) ? (L_ - 1) : pos);  // ref clips
        v[o] = *reinterpret_cast<const float4*>(embB + (size_t)pos * D_ + t * 4);
        w[o] = (o < n) ? 1.0f : 0.0f;
    }

    float4 acc = make_float4(0.f, 0.f, 0.f, 0.f);
#pragma unroll
    for (int o = 0; o < MSL_; ++o) {
        acc.x += v[o].x * w[o];
        acc.y += v[o].y * w[o];
        acc.z += v[o].z * w[o];
        acc.w += v[o].w * w[o];
    }

    const float scale = span_valid ? inv : 0.0f;
    float4 r;
    r.x = acc.x * scale;
    r.y = acc.y * scale;
    r.z = acc.z * scale;
    r.w = acc.w * scale;

    *reinterpret_cast<float4*>(out + (size_t)sp * D_ + t * 4) = r;

    if (t == 0) {
        // mask output lives after pooled: offset B*S*D + sp, written as 1.0/0.0
        out[(size_t)B_ * S_ * D_ + sp] = span_valid ? 1.0f : 0.0f;
    }
}

extern "C" void kernel_launch(void* const* d_in, const int* in_sizes, int n_in,
                              void* d_out, int out_size, void* d_ws, size_t ws_size,
                              hipStream_t stream) {
    const float* emb       = (const float*)d_in[0];
    const int*   span_pos  = (const int*)d_in[1];
    const int*   span_nums = (const int*)d_in[2];
    // d_in[3] (repeated_vector) is derivable / unused.
    float* out = (float*)d_out;

    span_mean_kernel<<<B_ * S_, 192, 0, stream>>>(emb, span_pos, span_nums, out);
}

// Round 3
// 14.103 us; speedup vs baseline: 1.0803x; 1.0403x over previous
//
#include <hip/hip_runtime.h>

// Problem constants (from reference)
#define B_ 64
#define L_ 2048
#define D_ 768
#define S_ 32
#define MSL_ 16

// One block per span, 192 threads, each thread owns one float4 of D=768.
// Gather is split into two 8-deep unconditional load batches: 8 loads in
// flight keeps VGPR ~60 (full 24 waves/CU occupancy) while 8-deep ILP x 24
// waves/CU is far beyond Little's-law needs (~9KB/CU in flight at 6.3TB/s).
// Out-of-span offsets clamp to the last valid row (cache hit) with weight 0.
// blockIdx is XCD-chunk-swizzled (bijective: 2048 = 8 XCD x 256) so all 32
// spans of a batch land on one XCD: overlapping span rows hit that XCD's L2
// instead of re-fetching HBM.
__global__ __launch_bounds__(192) void span_mean_kernel(
    const float* __restrict__ emb,      // (B, L, D)
    const int*   __restrict__ span_pos, // (B, S, 2)
    const int*   __restrict__ span_nums,// (B,)
    float*       __restrict__ out)      // pooled (B,S,D) then mask (B,S)
{
    // XCD-chunked swizzle: hw round-robins blockIdx across 8 XCDs; remap so
    // XCD x serves logical blocks [x*256, (x+1)*256) = 8 whole batches.
    const int bid = blockIdx.x;
    const int sp  = (bid & 7) * 256 + (bid >> 3);   // bijective for 2048

    const int b = sp >> 5;              // / S_ (S_ == 32)
    const int s = sp & (S_ - 1);        // % S_

    // Reference adds +1 to stored positions.
    const int2 pos2  = *reinterpret_cast<const int2*>(span_pos + sp * 2);
    const int  start = pos2.x + 1;
    const int  end   = pos2.y + 1;

    int n = end - start;
    n = n < 0 ? 0 : (n > MSL_ ? MSL_ : n);       // valid count = clamp(end-start, 0, 16)
    const int   cnt = n > 0 ? n : 1;             // max(count, 1)
    const float inv = 1.0f / (float)cnt;
    const bool  span_valid = (s < span_nums[b]);

    const int t = threadIdx.x;                   // 0..191, float4 lane within row

    const float* embB = emb + (size_t)b * L_ * D_;

    float4 acc = make_float4(0.f, 0.f, 0.f, 0.f);

#pragma unroll
    for (int half = 0; half < 2; ++half) {
        float4 v[8];
        float  w[8];
#pragma unroll
        for (int i = 0; i < 8; ++i) {
            const int o = half * 8 + i;
            int oo = (o < n) ? o : (n - 1);      // clamp (n>=1 per input spec)
            oo = oo < 0 ? 0 : oo;                // guard n==0
            int pos = start + oo;
            pos = pos < 0 ? 0 : (pos > (L_ - 1) ? (L_ - 1) : pos);  // ref clips
            v[i] = *reinterpret_cast<const float4*>(embB + (size_t)pos * D_ + t * 4);
            w[i] = (o < n) ? 1.0f : 0.0f;
        }
#pragma unroll
        for (int i = 0; i < 8; ++i) {
            acc.x += v[i].x * w[i];
            acc.y += v[i].y * w[i];
            acc.z += v[i].z * w[i];
            acc.w += v[i].w * w[i];
        }
    }

    const float scale = span_valid ? inv : 0.0f;
    float4 r;
    r.x = acc.x * scale;
    r.y = acc.y * scale;
    r.z = acc.z * scale;
    r.w = acc.w * scale;

    *reinterpret_cast<float4*>(out + (size_t)sp * D_ + t * 4) = r;

    if (t == 0) {
        // mask output lives after pooled: offset B*S*D + sp, written as 1.0/0.0
        out[(size_t)B_ * S_ * D_ + sp] = span_valid ? 1.0f : 0.0f;
    }
}

extern "C" void kernel_launch(void* const* d_in, const int* in_sizes, int n_in,
                              void* d_out, int out_size, void* d_ws, size_t ws_size,
                              hipStream_t stream) {
    const float* emb       = (const float*)d_in[0];
    const int*   span_pos  = (const int*)d_in[1];
    const int*   span_nums = (const int*)d_in[2];
    // d_in[3] (repeated_vector) is derivable / unused.
    float* out = (float*)d_out;

    span_mean_kernel<<<B_ * S_, 192, 0, stream>>>(emb, span_pos, span_nums, out);
}